// Round 5
// baseline (1453.212 us; speedup 1.0000x reference)
//
#include <hip/hip_runtime.h>

#define E_EDGES 262144
#define V_NODES 65536
#define D_DIM   256

typedef short bf16x8 __attribute__((ext_vector_type(8)));
typedef float f32x4  __attribute__((ext_vector_type(4)));

__device__ __forceinline__ unsigned short f2bf(float f) {
  union { float f; unsigned u; } x; x.f = f;
  unsigned r = x.u + 0x7FFFu + ((x.u >> 16) & 1u);
  return (unsigned short)(r >> 16);
}
__device__ __forceinline__ float bf2f(unsigned short h) {
  union { unsigned u; float f; } x; x.u = ((unsigned)h) << 16;
  return x.f;
}
__device__ __forceinline__ void async16(const void* g, void* l) {
  __builtin_amdgcn_global_load_lds(
      (const __attribute__((address_space(1))) unsigned*)g,
      (__attribute__((address_space(3))) unsigned*)l, 16, 0, 0);
}

// ---------------- weight convert + transpose to bf16 [N][K] ----------------
__global__ __launch_bounds__(256) void convert_weights_kernel(
    const float* __restrict__ W1, const float* __restrict__ W2,
    unsigned short* __restrict__ W1T, unsigned short* __restrict__ W2T) {
  int idx = blockIdx.x * 256 + threadIdx.x;           // 0 .. 655359
  {
    // W1T[i][n][k] (n<512,k<256)  <-  W1[i][k][n]
    int k = idx & 255, n = (idx >> 8) & 511, i = idx >> 17;
    W1T[idx] = f2bf(W1[((size_t)(i * 256 + k)) * 512 + n]);
  }
  {
    // W2T[i][n][k] (n<256,k<512)  <-  W2[i][k][n]
    int k = idx & 511, n = (idx >> 9) & 255, i = idx >> 17;
    W2T[idx] = f2bf(W2[((size_t)(i * 512 + k)) * 256 + n]);
  }
}

// ---------------- CSR build (by destination) ----------------
__global__ void hist_kernel(const int* __restrict__ ei, int* __restrict__ counts) {
  int e = blockIdx.x * 256 + threadIdx.x;
  int d = (e < E_EDGES) ? ei[E_EDGES + e] : (e - E_EDGES);
  atomicAdd(&counts[d], 1);
}
__global__ void scan1_kernel(const int* __restrict__ counts, int* __restrict__ indptr,
                             int* __restrict__ bsums) {
  __shared__ int s[256];
  int t = threadIdx.x, b = blockIdx.x;
  int v = counts[b * 256 + t];
  s[t] = v; __syncthreads();
  for (int off = 1; off < 256; off <<= 1) {
    int add = (t >= off) ? s[t - off] : 0;
    __syncthreads();
    s[t] += add;
    __syncthreads();
  }
  indptr[b * 256 + t] = s[t] - v;
  if (t == 255) bsums[b] = s[255];
}
__global__ void scan2_kernel(const int* __restrict__ bsums, int* __restrict__ boff) {
  __shared__ int s[256];
  int t = threadIdx.x;
  int v = bsums[t];
  s[t] = v; __syncthreads();
  for (int off = 1; off < 256; off <<= 1) {
    int add = (t >= off) ? s[t - off] : 0;
    __syncthreads();
    s[t] += add;
    __syncthreads();
  }
  boff[t] = s[t] - v;
}
__global__ void scan3_kernel(int* __restrict__ indptr, const int* __restrict__ boff) {
  int t = threadIdx.x, b = blockIdx.x;
  indptr[b * 256 + t] += boff[b];
  if (b == 0 && t == 0) indptr[V_NODES] = E_EDGES + V_NODES;
}
__global__ void scatter_kernel(const int* __restrict__ ei, const int* __restrict__ indptr,
                               int* __restrict__ fill, int* __restrict__ csr_eid) {
  int e = blockIdx.x * 256 + threadIdx.x;
  int d = (e < E_EDGES) ? ei[E_EDGES + e] : (e - E_EDGES);
  int pos = indptr[d] + atomicAdd(&fill[d], 1);
  csr_eid[pos] = e;
}

// ---------------- message passing: aggr = (1+eps)*h + sum relu(h[src]+eemb)*w  (fp32 out) ----------------
template <bool L0>
__device__ __forceinline__ void load_hnorm(int node, int c0, const float* __restrict__ x,
                                           const unsigned short* __restrict__ hprev,
                                           const float* sc, const float* sh, float* out) {
  if (L0) {
    const float* p = x + ((size_t)((node >> 8) * 257 + (node & 255) + 1)) * 256 + c0;
    float4 tv = *(const float4*)p;
    out[0] = tv.x; out[1] = tv.y; out[2] = tv.z; out[3] = tv.w;
  } else {
    ushort4 tv = *(const ushort4*)(hprev + (size_t)node * 256 + c0);
    out[0] = fmaxf(bf2f(tv.x) * sc[0] + sh[0], 0.f);
    out[1] = fmaxf(bf2f(tv.y) * sc[1] + sh[1], 0.f);
    out[2] = fmaxf(bf2f(tv.z) * sc[2] + sh[2], 0.f);
    out[3] = fmaxf(bf2f(tv.w) * sc[3] + sh[3], 0.f);
  }
}

template <bool L0>
__global__ __launch_bounds__(256) void msg_kernel(
    const float* __restrict__ x, const unsigned short* __restrict__ hprev,
    const float* __restrict__ scale2, const float* __restrict__ shift2,
    const int* __restrict__ indptr, const int* __restrict__ csr_eid,
    const int* __restrict__ ei, const int* __restrict__ ea, const float* __restrict__ ew,
    const float* __restrict__ bemb, const float* __restrict__ eps_param, int layer,
    float* __restrict__ aggr_f) {
  int wid = threadIdx.x >> 6;
  int lane = threadIdx.x & 63;
  int v = blockIdx.x * 4 + wid;
  int c0 = lane * 4;
  float ep = 1.0f + eps_param[layer];

  float sc[4], sh[4];
  if (!L0) {
#pragma unroll
    for (int j = 0; j < 4; ++j) { sc[j] = scale2[c0 + j]; sh[j] = shift2[c0 + j]; }
  }

  float hv[4];
  load_hnorm<L0>(v, c0, x, hprev, sc, sh, hv);
  float acc[4] = { ep * hv[0], ep * hv[1], ep * hv[2], ep * hv[3] };

  int beg = indptr[v], end = indptr[v + 1];
  for (int p = beg; p < end; ++p) {
    int eid = csr_eid[p];
    int s, a0, a1, a2; float w;
    if (eid < E_EDGES) {
      s = ei[eid];
      a0 = ea[eid * 3]; a1 = ea[eid * 3 + 1]; a2 = ea[eid * 3 + 2];
      w = ew[eid];
    } else {
      s = eid - E_EDGES; a0 = 5; a1 = 7; a2 = 0; w = 1.0f;
    }
    float hs[4];
    load_hnorm<L0>(s, c0, x, hprev, sc, sh, hs);
    float4 e0 = *(const float4*)(bemb + (size_t)(0 * 16 + a0) * 256 + c0);
    float4 e1 = *(const float4*)(bemb + (size_t)(1 * 16 + a1) * 256 + c0);
    float4 e2 = *(const float4*)(bemb + (size_t)(2 * 16 + a2) * 256 + c0);
    acc[0] += fmaxf(hs[0] + e0.x + e1.x + e2.x, 0.f) * w;
    acc[1] += fmaxf(hs[1] + e0.y + e1.y + e2.y, 0.f) * w;
    acc[2] += fmaxf(hs[2] + e0.z + e1.z + e2.z, 0.f) * w;
    acc[3] += fmaxf(hs[3] + e0.w + e1.w + e2.w, 0.f) * w;
  }
  float4 o; o.x = acc[0]; o.y = acc[1]; o.z = acc[2]; o.w = acc[3];
  *(float4*)(aggr_f + (size_t)v * 256 + c0) = o;
}

// ---------------- column sums of fp32 aggr (for BN-invariant centering) ----------------
__global__ __launch_bounds__(256) void colsum_kernel(const float* __restrict__ aggr_f,
                                                     float* __restrict__ colsum) {
  int t = threadIdx.x;
  size_t base = (size_t)blockIdx.x * 64 * 256 + t;
  float s = 0.f;
#pragma unroll
  for (int r = 0; r < 64; ++r) s += aggr_f[base + (size_t)r * 256];
  atomicAdd(&colsum[t], s);
}

// ---------------- center columns + convert to bf16 (BN shift-invariance makes this exact) ----------------
__global__ __launch_bounds__(256) void center_kernel(const float* __restrict__ aggr_f,
                                                     const float* __restrict__ colsum,
                                                     unsigned short* __restrict__ aggr_c) {
  size_t i = ((size_t)blockIdx.x * 256 + threadIdx.x) * 4;
  int c = (int)(i & 255);
  float4 v = *(const float4*)(aggr_f + i);
  const float inv = 1.0f / 65536.0f;
  ushort4 o;
  o.x = f2bf(v.x - colsum[c + 0] * inv);
  o.y = f2bf(v.y - colsum[c + 1] * inv);
  o.z = f2bf(v.z - colsum[c + 2] * inv);
  o.w = f2bf(v.w - colsum[c + 3] * inv);
  *(ushort4*)(aggr_c + i) = o;
}

// ---------------- bf16 MFMA GEMM: C[V][N] = A[V][K] @ BT[N][K]^T + bias, + column stats ----------------
template <int K, int N>
__global__ __launch_bounds__(256) void gemm_kernel(
    const unsigned short* __restrict__ A, const unsigned short* __restrict__ BT,
    const float* __restrict__ bias, unsigned short* __restrict__ C,
    float* __restrict__ sumP, float* __restrict__ sqP) {
  __shared__ char lds[16384];  // [0,8K)=A tile [128][32] bf16, [8K,16K)=B tile [128][32]
  const int t = threadIdx.x;
  const int lane = t & 63;
  const int wid = t >> 6;
  const int waveM = wid >> 1, waveN = wid & 1;
  const int rowBase = blockIdx.x * 128;
  const int colBase = blockIdx.y * 128;
  const int kw = lane >> 4;
  const int l15 = lane & 15;

  f32x4 acc[4][4];
#pragma unroll
  for (int m = 0; m < 4; ++m)
#pragma unroll
    for (int n = 0; n < 4; ++n) acc[m][n] = (f32x4){0.f, 0.f, 0.f, 0.f};

  for (int k0 = 0; k0 < K; k0 += 32) {
#pragma unroll
    for (int c = 0; c < 2; ++c) {
      int row = c * 64 + (t >> 2);
      int gslot = (t & 3) ^ ((row >> 1) & 3);   // pre-swizzled global source
      const unsigned short* ga = A + (size_t)(rowBase + row) * K + k0 + gslot * 8;
      async16(ga, lds + c * 4096 + wid * 1024);
      const unsigned short* gb = BT + (size_t)(colBase + row) * K + k0 + gslot * 8;
      async16(gb, lds + 8192 + c * 4096 + wid * 1024);
    }
    __syncthreads();   // compiler drains vmcnt before s_barrier

    bf16x8 af[4], bfr[4];
#pragma unroll
    for (int f = 0; f < 4; ++f) {
      int rA = waveM * 64 + f * 16 + l15;
      af[f] = *(const bf16x8*)(lds + rA * 64 + ((kw ^ ((rA >> 1) & 3)) * 16));
      int rB = waveN * 64 + f * 16 + l15;
      bfr[f] = *(const bf16x8*)(lds + 8192 + rB * 64 + ((kw ^ ((rB >> 1) & 3)) * 16));
    }
#pragma unroll
    for (int m = 0; m < 4; ++m)
#pragma unroll
      for (int n = 0; n < 4; ++n)
        acc[m][n] = __builtin_amdgcn_mfma_f32_16x16x32_bf16(af[m], bfr[n], acc[m][n], 0, 0, 0);
    __syncthreads();
  }

  const int cB = colBase + waveN * 64;
  const int rB0 = rowBase + waveM * 64;
#pragma unroll
  for (int n = 0; n < 4; ++n) {
    int col = cB + n * 16 + l15;
    float bcol = bias[col];
    float psum = 0.f, psq = 0.f;
#pragma unroll
    for (int m = 0; m < 4; ++m) {
#pragma unroll
      for (int r = 0; r < 4; ++r) {
        float val = acc[m][n][r] + bcol;
        int row = rB0 + m * 16 + kw * 4 + r;
        C[(size_t)row * N + col] = f2bf(val);
        psum += val; psq += val * val;
      }
    }
    psum += __shfl_xor(psum, 16); psum += __shfl_xor(psum, 32);
    psq  += __shfl_xor(psq, 16);  psq  += __shfl_xor(psq, 32);
    if (kw == 0) {
      int prow = blockIdx.x * 2 + waveM;
      sumP[(size_t)prow * N + col] = psum;
      sqP[(size_t)prow * N + col] = psq;
    }
  }
}

// ---------------- per-column batchnorm scale/shift ----------------
__global__ void finalize_kernel(const float* __restrict__ sumP, const float* __restrict__ sqP,
                                const float* __restrict__ g, const float* __restrict__ b,
                                float* __restrict__ scale, float* __restrict__ shift, int N) {
  __shared__ float ls[256], lq[256];
  int col = blockIdx.x, t = threadIdx.x;
  float s = 0.f, q = 0.f;
  for (int r = t; r < 1024; r += 256) {
    s += sumP[(size_t)r * N + col];
    q += sqP[(size_t)r * N + col];
  }
  ls[t] = s; lq[t] = q; __syncthreads();
  for (int off = 128; off > 0; off >>= 1) {
    if (t < off) { ls[t] += ls[t + off]; lq[t] += lq[t + off]; }
    __syncthreads();
  }
  if (t == 0) {
    float inv = 1.0f / 65536.0f;
    float mu = ls[0] * inv;
    float var = lq[0] * inv - mu * mu;
    float sc = g[col] * rsqrtf(var + 1e-5f);
    scale[col] = sc;
    shift[col] = b[col] - mu * sc;
  }
}

// ---------------- in-place bn+relu on z1 [V][512] bf16 ----------------
__global__ __launch_bounds__(256) void apply_bn_relu_kernel(
    unsigned short* __restrict__ z, const float* __restrict__ scale,
    const float* __restrict__ shift) {
  size_t i = ((size_t)blockIdx.x * 256 + threadIdx.x) * 8;
  int col = (int)(i & 511);
  ushort4 a = *(const ushort4*)(z + i);
  ushort4 b = *(const ushort4*)(z + i + 4);
  float f0 = fmaxf(bf2f(a.x) * scale[col + 0] + shift[col + 0], 0.f);
  float f1 = fmaxf(bf2f(a.y) * scale[col + 1] + shift[col + 1], 0.f);
  float f2 = fmaxf(bf2f(a.z) * scale[col + 2] + shift[col + 2], 0.f);
  float f3 = fmaxf(bf2f(a.w) * scale[col + 3] + shift[col + 3], 0.f);
  float f4 = fmaxf(bf2f(b.x) * scale[col + 4] + shift[col + 4], 0.f);
  float f5 = fmaxf(bf2f(b.y) * scale[col + 5] + shift[col + 5], 0.f);
  float f6 = fmaxf(bf2f(b.z) * scale[col + 6] + shift[col + 6], 0.f);
  float f7 = fmaxf(bf2f(b.w) * scale[col + 7] + shift[col + 7], 0.f);
  ushort4 oa, ob;
  oa.x = f2bf(f0); oa.y = f2bf(f1); oa.z = f2bf(f2); oa.w = f2bf(f3);
  ob.x = f2bf(f4); ob.y = f2bf(f5); ob.z = f2bf(f6); ob.w = f2bf(f7);
  *(ushort4*)(z + i) = oa;
  *(ushort4*)(z + i + 4) = ob;
}

// ---------------- final: out = x; out[:,1:,:] += mask * bn2(z2) ----------------
__global__ void final_out_kernel(const float* __restrict__ x, const unsigned short* __restrict__ z2,
                                 const float* __restrict__ scale2, const float* __restrict__ shift2,
                                 const int* __restrict__ xmask, float* __restrict__ out) {
  int row = blockIdx.x;   // 0..256
  int b = blockIdx.y;     // 0..255
  int lane = threadIdx.x; // 0..63
  size_t off = ((size_t)b * 257 + row) * 256 + lane * 4;
  float4 xv = *(const float4*)(x + off);
  if (row > 0) {
    int v = b * 256 + (row - 1);
    float m = (float)xmask[v];
    ushort4 tv = *(const ushort4*)(z2 + (size_t)v * 256 + lane * 4);
    int c = lane * 4;
    xv.x += m * (bf2f(tv.x) * scale2[c + 0] + shift2[c + 0]);
    xv.y += m * (bf2f(tv.y) * scale2[c + 1] + shift2[c + 1]);
    xv.z += m * (bf2f(tv.z) * scale2[c + 2] + shift2[c + 2]);
    xv.w += m * (bf2f(tv.w) * scale2[c + 3] + shift2[c + 3]);
  }
  *(float4*)(out + off) = xv;
}

extern "C" void kernel_launch(void* const* d_in, const int* in_sizes, int n_in,
                              void* d_out, int out_size, void* d_ws, size_t ws_size,
                              hipStream_t stream) {
  const float* x    = (const float*)d_in[0];
  const float* ew   = (const float*)d_in[1];
  const float* bemb = (const float*)d_in[2];
  const float* W1   = (const float*)d_in[3];
  const float* b1   = (const float*)d_in[4];
  const float* g1   = (const float*)d_in[5];
  const float* bb1  = (const float*)d_in[6];
  const float* W2   = (const float*)d_in[7];
  const float* b2   = (const float*)d_in[8];
  const float* g2   = (const float*)d_in[9];
  const float* bb2  = (const float*)d_in[10];
  const float* eps  = (const float*)d_in[11];
  const int* xmask  = (const int*)d_in[12];
  const int* ei     = (const int*)d_in[13];
  const int* ea     = (const int*)d_in[14];
  float* out = (float*)d_out;

  char* ws = (char*)d_ws;
  size_t off = 0;
  auto alloc = [&](size_t bytes) {
    char* p = ws + off;
    off += (bytes + 255) & ~(size_t)255;
    return p;
  };
  unsigned short* W1T = (unsigned short*)alloc(5ull * 512 * 256 * 2);
  unsigned short* W2T = (unsigned short*)alloc(5ull * 256 * 512 * 2);
  int* counts = (int*)alloc(65536ull * 4);
  int* fill   = (int*)alloc(65536ull * 4);
  int* indptr = (int*)alloc(65537ull * 4);
  int* bsums  = (int*)alloc(256 * 4);
  int* boff   = (int*)alloc(256 * 4);
  int* csr    = (int*)alloc(327680ull * 4);
  float* scale1 = (float*)alloc(512 * 4);
  float* shift1 = (float*)alloc(512 * 4);
  float* scale2 = (float*)alloc(256 * 4);
  float* shift2 = (float*)alloc(256 * 4);
  float* colsum = (float*)alloc(256 * 4);
  float* sumP = (float*)alloc(1024ull * 512 * 4);
  float* sqP  = (float*)alloc(1024ull * 512 * 4);
  float* aggr_f = (float*)alloc(65536ull * 256 * 4);
  unsigned short* aggr_c = (unsigned short*)alloc(65536ull * 256 * 2);
  unsigned short* z1   = (unsigned short*)alloc(65536ull * 512 * 2);
  unsigned short* z2   = (unsigned short*)alloc(65536ull * 256 * 2);
  (void)ws_size; (void)in_sizes; (void)n_in; (void)out_size;

  hipMemsetAsync(counts, 0, 65536ull * 4, stream);
  hipMemsetAsync(fill, 0, 65536ull * 4, stream);

  convert_weights_kernel<<<2560, 256, 0, stream>>>(W1, W2, W1T, W2T);
  hist_kernel<<<1280, 256, 0, stream>>>(ei, counts);
  scan1_kernel<<<256, 256, 0, stream>>>(counts, indptr, bsums);
  scan2_kernel<<<1, 256, 0, stream>>>(bsums, boff);
  scan3_kernel<<<256, 256, 0, stream>>>(indptr, boff);
  scatter_kernel<<<1280, 256, 0, stream>>>(ei, indptr, fill, csr);

  for (int i = 0; i < 5; ++i) {
    const float* bemb_l = bemb + (size_t)i * 3 * 16 * 256;
    if (i == 0)
      msg_kernel<true><<<16384, 256, 0, stream>>>(x, (const unsigned short*)nullptr, nullptr, nullptr,
                                                  indptr, csr, ei, ea, ew, bemb_l, eps, i, aggr_f);
    else
      msg_kernel<false><<<16384, 256, 0, stream>>>(x, z2, scale2, shift2,
                                                   indptr, csr, ei, ea, ew, bemb_l, eps, i, aggr_f);
    hipMemsetAsync(colsum, 0, 256 * 4, stream);
    colsum_kernel<<<1024, 256, 0, stream>>>(aggr_f, colsum);
    center_kernel<<<16384, 256, 0, stream>>>(aggr_f, colsum, aggr_c);
    gemm_kernel<256, 512><<<dim3(512, 4), 256, 0, stream>>>(
        aggr_c, W1T + (size_t)i * 512 * 256, b1 + i * 512, z1, sumP, sqP);
    finalize_kernel<<<512, 256, 0, stream>>>(sumP, sqP, g1 + i * 512, bb1 + i * 512,
                                             scale1, shift1, 512);
    apply_bn_relu_kernel<<<16384, 256, 0, stream>>>(z1, scale1, shift1);
    gemm_kernel<512, 256><<<dim3(512, 2), 256, 0, stream>>>(
        z1, W2T + (size_t)i * 256 * 512, b2 + i * 256, z2, sumP, sqP);
    finalize_kernel<<<256, 256, 0, stream>>>(sumP, sqP, g2 + i * 256, bb2 + i * 256,
                                             scale2, shift2, 256);
  }
  final_out_kernel<<<dim3(257, 256), 64, 0, stream>>>(x, z2, scale2, shift2, xmask, out);
}